// Round 1
// baseline (106.721 us; speedup 1.0000x reference)
//
#include <hip/hip_runtime.h>
#include <hip/hip_bf16.h>

#define TLEN 4096
#define KTAPS 256

// Kernel 1: compute GL coefficients w[0..255] into d_ws.
// w_0 = 1, w_j = w_{j-1} * (j-1-alpha)/j ; alpha = loc + softplus(scale)*eps.
__global__ void gl_coeff_kernel(const float* __restrict__ loc,
                                const float* __restrict__ scale,
                                const float* __restrict__ eps,
                                float* __restrict__ w_out) {
    __shared__ float s[KTAPS];
    const int j = threadIdx.x;
    const float alpha = loc[0] + log1pf(expf(scale[0])) * eps[0];
    float f = (j == 0) ? 1.0f : (((float)j - 1.0f - alpha) / (float)j);
    s[j] = f;
    __syncthreads();
    // inclusive product scan (Hillis-Steele)
    #pragma unroll
    for (int st = 1; st < KTAPS; st <<= 1) {
        float v = s[j];
        float p = (j >= st) ? s[j - st] : 1.0f;
        __syncthreads();
        s[j] = v * p;
        __syncthreads();
    }
    w_out[j] = s[j];
}

// Kernel 2: causal conv, one row (4096) per block, 256 threads.
// Each thread computes 16 outputs = 4 groups of 4 contiguous positions.
__global__ void __launch_bounds__(256)
frac_conv_kernel(const float* __restrict__ x,
                 const float* __restrict__ w,
                 float* __restrict__ out) {
    __shared__ __align__(16) float xs[KTAPS + TLEN];  // xs[256+q] = x[q], xs[0..255]=0
    __shared__ __align__(16) float wl[KTAPS];

    const int row = blockIdx.x;
    const int tid = threadIdx.x;
    const float* __restrict__ xr = x + (size_t)row * TLEN;
    float* __restrict__ orow = out + (size_t)row * TLEN;

    // zero left halo (256 floats = 64 float4)
    if (tid < 64) ((float4*)xs)[tid] = make_float4(0.f, 0.f, 0.f, 0.f);
    // stage the row (4096 floats = 1024 float4)
    float4* xs4w = (float4*)(xs + KTAPS);
    const float4* xr4 = (const float4*)xr;
    #pragma unroll
    for (int k = 0; k < 4; ++k) xs4w[tid + k * 256] = xr4[tid + k * 256];
    // stage taps
    if (tid < 64) ((float4*)wl)[tid] = ((const float4*)w)[tid];
    __syncthreads();

    const float4* __restrict__ xsv = (const float4*)xs;  // xsv[64 + q/4] = x[q..q+3]

    float4 acc[4];
    float4 lo[4], hi[4];
    int n0[4];
    #pragma unroll
    for (int g = 0; g < 4; ++g) {
        n0[g] = (tid << 2) + (g << 10);
        acc[g] = make_float4(0.f, 0.f, 0.f, 0.f);
        const int c = n0[g] >> 2;       // chunk index of x[n0..n0+3]
        hi[g] = xsv[64 + c];            // x[n0 .. n0+3]
        lo[g] = xsv[63 + c];            // x[n0-4 .. n0-1] (zeros for n0=0)
    }

    // main loop over taps, 4 at a time; last step (j=252) peeled (no next-load)
    #pragma unroll 4
    for (int j = 0; j < KTAPS - 4; j += 4) {
        const float4 w4 = *(const float4*)(wl + j);
        #pragma unroll
        for (int g = 0; g < 4; ++g) {
            acc[g].x += w4.x*hi[g].x + w4.y*lo[g].w + w4.z*lo[g].z + w4.w*lo[g].y;
            acc[g].y += w4.x*hi[g].y + w4.y*hi[g].x + w4.z*lo[g].w + w4.w*lo[g].z;
            acc[g].z += w4.x*hi[g].z + w4.y*hi[g].y + w4.z*hi[g].x + w4.w*lo[g].w;
            acc[g].w += w4.x*hi[g].w + w4.y*hi[g].z + w4.z*hi[g].y + w4.w*hi[g].x;
            hi[g] = lo[g];
            lo[g] = xsv[64 + ((n0[g] - j - 8) >> 2)];  // min index 0 (halo), in-bounds
        }
    }
    {   // j = 252
        const float4 w4 = *(const float4*)(wl + (KTAPS - 4));
        #pragma unroll
        for (int g = 0; g < 4; ++g) {
            acc[g].x += w4.x*hi[g].x + w4.y*lo[g].w + w4.z*lo[g].z + w4.w*lo[g].y;
            acc[g].y += w4.x*hi[g].y + w4.y*hi[g].x + w4.z*lo[g].w + w4.w*lo[g].z;
            acc[g].z += w4.x*hi[g].z + w4.y*hi[g].y + w4.z*hi[g].x + w4.w*lo[g].w;
            acc[g].w += w4.x*hi[g].w + w4.y*hi[g].z + w4.z*hi[g].y + w4.w*hi[g].x;
        }
    }

    #pragma unroll
    for (int g = 0; g < 4; ++g) {
        *(float4*)(orow + n0[g]) = acc[g];
    }
}

extern "C" void kernel_launch(void* const* d_in, const int* in_sizes, int n_in,
                              void* d_out, int out_size, void* d_ws, size_t ws_size,
                              hipStream_t stream) {
    const float* x     = (const float*)d_in[0];
    const float* loc   = (const float*)d_in[1];
    const float* scale = (const float*)d_in[2];
    const float* eps   = (const float*)d_in[3];
    // d_in[4] = k (int), fixed at 256 for this problem.

    float* w = (float*)d_ws;           // 256 floats of scratch
    float* out = (float*)d_out;

    const int rows = in_sizes[0] / TLEN;  // B*C = 2048

    gl_coeff_kernel<<<1, KTAPS, 0, stream>>>(loc, scale, eps, w);
    frac_conv_kernel<<<rows, 256, 0, stream>>>(x, w, out);
}

// Round 2
// 45.773 us; speedup vs baseline: 2.3315x; 2.3315x over previous
//
#include <hip/hip_runtime.h>
#include <hip/hip_bf16.h>

#define TLEN 4096
#define KTAPS 256

typedef __attribute__((ext_vector_type(8))) unsigned short ushort8v;
typedef __attribute__((ext_vector_type(8))) __bf16 bf16x8;
typedef __attribute__((ext_vector_type(16))) float f32x16;

// ---------------- Kernel 1 (MFMA path): GL coeffs -> Toeplitz A-fragments ----------------
// A-tile d (d=0..17): W_d[m][k] = w[256 - 16d + m - k], m in [0,32), k in [0,16), 0 outside [0,256).
// Fragment layout for mfma_f32_32x32x16_bf16 A-operand: lane l holds row m=l&31,
// k = 8*(l>>5)+e, e=0..7. Stored as ushort (bf16 bits): Afrags[d*512 + lane*8 + e].
// hi tiles at [0, 9216), lo tiles at [9216, 18432).
__global__ void gl_coeff_frag_kernel(const float* __restrict__ loc,
                                     const float* __restrict__ scale,
                                     const float* __restrict__ eps,
                                     unsigned short* __restrict__ Afrags) {
    __shared__ float s[KTAPS];
    const int j = threadIdx.x;
    const float alpha = loc[0] + log1pf(expf(scale[0])) * eps[0];
    float f = (j == 0) ? 1.0f : (((float)j - 1.0f - alpha) / (float)j);
    s[j] = f;
    __syncthreads();
    #pragma unroll
    for (int st = 1; st < KTAPS; st <<= 1) {
        float v = s[j];
        float p = (j >= st) ? s[j - st] : 1.0f;
        __syncthreads();
        s[j] = v * p;
        __syncthreads();
    }
    // build fragments: 18 tiles * 512 elements
    for (int fi = j; fi < 18 * 512; fi += 256) {
        const int tile = fi >> 9;
        const int lane = (fi >> 3) & 63;
        const int e    = fi & 7;
        const int m    = lane & 31;
        const int k    = 8 * (lane >> 5) + e;
        const int idx  = 256 - 16 * tile + m - k;
        const float wv = (idx >= 0 && idx < KTAPS) ? s[idx] : 0.0f;
        __hip_bfloat16 h = __float2bfloat16(wv);
        const float hf = __bfloat162float(h);
        __hip_bfloat16 l = __float2bfloat16(wv - hf);
        Afrags[fi]            = *(unsigned short*)&h;
        Afrags[18 * 512 + fi] = *(unsigned short*)&l;
    }
}

// ---------------- Kernel 2 (MFMA path): Toeplitz conv ----------------
// Grid: (rows/32)*8 blocks of 256 threads (4 waves). Block b: rowtile=b>>3, sgroup=b&7.
// Wave w handles strip s = sgroup*512 + w*128: outputs [s, s+128) for 32 rows.
// Window: t in [s-256, s+128) = 24 chunks of 16. D-tiles: u=0..3, n0=s+32u,
// chunks c=2u+d, A-tile d, d=0..17. 3 passes: Ah*Bh + Ah*Bl + Al*Bh (fp32 acc).
__global__ void __launch_bounds__(256, 2)
frac_conv_mfma(const float* __restrict__ x,
               const unsigned short* __restrict__ Afrags,
               float* __restrict__ out) {
    const int tid  = threadIdx.x;
    const int wave = tid >> 6;
    const int lane = tid & 63;
    const int l5   = lane >> 5;   // k-half selector
    const int ln   = lane & 31;   // row within tile (B/N dim) / A row (M dim)
    const int rowtile = blockIdx.x >> 3;
    const int sgroup  = blockIdx.x & 7;
    const int s = sgroup * 512 + wave * 128;
    const int row = rowtile * 32 + ln;
    const float* __restrict__ xr = x + (size_t)row * TLEN;
    float* __restrict__ orow = out + (size_t)row * TLEN;

    // ---- A fragments (registers) ----
    bf16x8 Ah[18], Al[18];
    #pragma unroll
    for (int d = 0; d < 18; ++d) {
        Ah[d] = __builtin_bit_cast(bf16x8, *(const ushort8v*)(Afrags + d * 512 + lane * 8));
        Al[d] = __builtin_bit_cast(bf16x8, *(const ushort8v*)(Afrags + 18 * 512 + d * 512 + lane * 8));
    }

    // ---- B chunks: load x, split fp32 -> bf16 hi + lo ----
    // Chunk c: B[k][r] = x[row0+r][t0+k], t0 = s-256+16c.
    // Lane l: col r=l&31 (its row), k=8*l5+e -> 8 consecutive fp32.
    bf16x8 Bh[24], Bl[24];
    #pragma unroll
    for (int c = 0; c < 24; ++c) {
        const int t0 = s - 256 + 16 * c;
        if (t0 < 0) {
            const ushort8v z = {0, 0, 0, 0, 0, 0, 0, 0};
            Bh[c] = __builtin_bit_cast(bf16x8, z);
            Bl[c] = __builtin_bit_cast(bf16x8, z);
        } else {
            const float* p = xr + t0 + 8 * l5;
            const float4 v0 = *(const float4*)(p);
            const float4 v1 = *(const float4*)(p + 4);
            const float vf[8] = {v0.x, v0.y, v0.z, v0.w, v1.x, v1.y, v1.z, v1.w};
            ushort8v hb, lb;
            #pragma unroll
            for (int e = 0; e < 8; ++e) {
                const unsigned int u  = __float_as_uint(vf[e]);
                const unsigned int ht = u & 0xFFFF0000u;           // truncated hi
                const float lf = vf[e] - __uint_as_float(ht);       // exact remainder
                hb[e] = (unsigned short)(ht >> 16);
                lb[e] = (unsigned short)(__float_as_uint(lf) >> 16);
            }
            Bh[c] = __builtin_bit_cast(bf16x8, hb);
            Bl[c] = __builtin_bit_cast(bf16x8, lb);
        }
    }

    // ---- MFMA: 4 D-tiles of 32 outputs x 32 rows ----
    #pragma unroll
    for (int u = 0; u < 4; ++u) {
        f32x16 acc = {0.f, 0.f, 0.f, 0.f, 0.f, 0.f, 0.f, 0.f,
                      0.f, 0.f, 0.f, 0.f, 0.f, 0.f, 0.f, 0.f};
        #pragma unroll
        for (int d = 0; d < 18; ++d) {
            const int c = 2 * u + d;
            acc = __builtin_amdgcn_mfma_f32_32x32x16_bf16(Ah[d], Bh[c], acc, 0, 0, 0);
            acc = __builtin_amdgcn_mfma_f32_32x32x16_bf16(Ah[d], Bl[c], acc, 0, 0, 0);
            acc = __builtin_amdgcn_mfma_f32_32x32x16_bf16(Al[d], Bh[c], acc, 0, 0, 0);
        }
        // D layout: col = lane&31 (channel row), m = (reg&3) + 8*(reg>>2) + 4*l5
        const int n0 = s + 32 * u;
        #pragma unroll
        for (int g = 0; g < 4; ++g) {
            const float4 o = make_float4(acc[4 * g + 0], acc[4 * g + 1],
                                         acc[4 * g + 2], acc[4 * g + 3]);
            *(float4*)(orow + n0 + 8 * g + 4 * l5) = o;
        }
    }
}

// ---------------- Fallback path (proven round-1 fp32 kernels) ----------------
__global__ void gl_coeff_kernel(const float* __restrict__ loc,
                                const float* __restrict__ scale,
                                const float* __restrict__ eps,
                                float* __restrict__ w_out) {
    __shared__ float s[KTAPS];
    const int j = threadIdx.x;
    const float alpha = loc[0] + log1pf(expf(scale[0])) * eps[0];
    float f = (j == 0) ? 1.0f : (((float)j - 1.0f - alpha) / (float)j);
    s[j] = f;
    __syncthreads();
    #pragma unroll
    for (int st = 1; st < KTAPS; st <<= 1) {
        float v = s[j];
        float p = (j >= st) ? s[j - st] : 1.0f;
        __syncthreads();
        s[j] = v * p;
        __syncthreads();
    }
    w_out[j] = s[j];
}

__global__ void __launch_bounds__(256)
frac_conv_kernel(const float* __restrict__ x,
                 const float* __restrict__ w,
                 float* __restrict__ out) {
    __shared__ __align__(16) float xs[KTAPS + TLEN];
    __shared__ __align__(16) float wl[KTAPS];
    const int row = blockIdx.x;
    const int tid = threadIdx.x;
    const float* __restrict__ xr = x + (size_t)row * TLEN;
    float* __restrict__ orow = out + (size_t)row * TLEN;
    if (tid < 64) ((float4*)xs)[tid] = make_float4(0.f, 0.f, 0.f, 0.f);
    float4* xs4w = (float4*)(xs + KTAPS);
    const float4* xr4 = (const float4*)xr;
    #pragma unroll
    for (int k = 0; k < 4; ++k) xs4w[tid + k * 256] = xr4[tid + k * 256];
    if (tid < 64) ((float4*)wl)[tid] = ((const float4*)w)[tid];
    __syncthreads();
    const float4* __restrict__ xsv = (const float4*)xs;
    float4 acc[4]; float4 lo[4], hi[4]; int n0[4];
    #pragma unroll
    for (int g = 0; g < 4; ++g) {
        n0[g] = (tid << 2) + (g << 10);
        acc[g] = make_float4(0.f, 0.f, 0.f, 0.f);
        const int c = n0[g] >> 2;
        hi[g] = xsv[64 + c];
        lo[g] = xsv[63 + c];
    }
    #pragma unroll 4
    for (int j = 0; j < KTAPS - 4; j += 4) {
        const float4 w4 = *(const float4*)(wl + j);
        #pragma unroll
        for (int g = 0; g < 4; ++g) {
            acc[g].x += w4.x*hi[g].x + w4.y*lo[g].w + w4.z*lo[g].z + w4.w*lo[g].y;
            acc[g].y += w4.x*hi[g].y + w4.y*hi[g].x + w4.z*lo[g].w + w4.w*lo[g].z;
            acc[g].z += w4.x*hi[g].z + w4.y*hi[g].y + w4.z*hi[g].x + w4.w*lo[g].w;
            acc[g].w += w4.x*hi[g].w + w4.y*hi[g].z + w4.z*hi[g].y + w4.w*hi[g].x;
            hi[g] = lo[g];
            lo[g] = xsv[64 + ((n0[g] - j - 8) >> 2)];
        }
    }
    {
        const float4 w4 = *(const float4*)(wl + (KTAPS - 4));
        #pragma unroll
        for (int g = 0; g < 4; ++g) {
            acc[g].x += w4.x*hi[g].x + w4.y*lo[g].w + w4.z*lo[g].z + w4.w*lo[g].y;
            acc[g].y += w4.x*hi[g].y + w4.y*hi[g].x + w4.z*lo[g].w + w4.w*lo[g].z;
            acc[g].z += w4.x*hi[g].z + w4.y*hi[g].y + w4.z*hi[g].x + w4.w*lo[g].w;
            acc[g].w += w4.x*hi[g].w + w4.y*hi[g].z + w4.z*hi[g].y + w4.w*hi[g].x;
        }
    }
    #pragma unroll
    for (int g = 0; g < 4; ++g) *(float4*)(orow + n0[g]) = acc[g];
}

extern "C" void kernel_launch(void* const* d_in, const int* in_sizes, int n_in,
                              void* d_out, int out_size, void* d_ws, size_t ws_size,
                              hipStream_t stream) {
    const float* x     = (const float*)d_in[0];
    const float* loc   = (const float*)d_in[1];
    const float* scale = (const float*)d_in[2];
    const float* eps   = (const float*)d_in[3];
    float* out = (float*)d_out;
    const int rows = in_sizes[0] / TLEN;  // 2048

    const size_t neededA = 1024 + (size_t)2 * 18 * 512 * 2;  // 37888 B
    if (ws_size >= neededA && (rows % 32) == 0) {
        unsigned short* A = (unsigned short*)((char*)d_ws + 1024);
        gl_coeff_frag_kernel<<<1, 256, 0, stream>>>(loc, scale, eps, A);
        frac_conv_mfma<<<(rows / 32) * 8, 256, 0, stream>>>(x, A, out);
    } else {
        float* w = (float*)d_ws;
        gl_coeff_kernel<<<1, 256, 0, stream>>>(loc, scale, eps, w);
        frac_conv_kernel<<<rows, 256, 0, stream>>>(x, w, out);
    }
}

// Round 3
// 39.895 us; speedup vs baseline: 2.6751x; 1.1473x over previous
//
#include <hip/hip_runtime.h>
#include <hip/hip_bf16.h>

#define TLEN 4096
#define KTAPS 256
#define NT 18     // Toeplitz A tiles per output tile (K window = 288 = 18*16)
#define NCH 20    // B chunks per 64-output wave slab

typedef __attribute__((ext_vector_type(8))) unsigned short ushort8v;
typedef __attribute__((ext_vector_type(8))) __bf16 bf16x8;
typedef __attribute__((ext_vector_type(16))) float f32x16;

// ---------------- Kernel 1: GL coeffs -> Toeplitz A-fragments (hi/lo bf16) ----------------
// A-tile d: W_d[m][k] = w[256 - 16d + m - k], m in [0,32), k in [0,16), 0 outside [0,256).
// mfma_f32_32x32x16_bf16 A layout: lane l holds row m=l&31, k = 8*(l>>5)+e.
// Afrags[d*512 + lane*8 + e]; hi at [0, 9216), lo at [9216, 18432).
__global__ void gl_coeff_frag_kernel(const float* __restrict__ loc,
                                     const float* __restrict__ scale,
                                     const float* __restrict__ eps,
                                     unsigned short* __restrict__ Afrags) {
    __shared__ float s[KTAPS];
    const int j = threadIdx.x;
    const float alpha = loc[0] + log1pf(expf(scale[0])) * eps[0];
    float f = (j == 0) ? 1.0f : (((float)j - 1.0f - alpha) / (float)j);
    s[j] = f;
    __syncthreads();
    #pragma unroll
    for (int st = 1; st < KTAPS; st <<= 1) {
        float v = s[j];
        float p = (j >= st) ? s[j - st] : 1.0f;
        __syncthreads();
        s[j] = v * p;
        __syncthreads();
    }
    for (int fi = j; fi < NT * 512; fi += 256) {
        const int tile = fi >> 9;
        const int lane = (fi >> 3) & 63;
        const int e    = fi & 7;
        const int m    = lane & 31;
        const int k    = 8 * (lane >> 5) + e;
        const int idx  = 256 - 16 * tile + m - k;
        const float wv = (idx >= 0 && idx < KTAPS) ? s[idx] : 0.0f;
        __hip_bfloat16 h = __float2bfloat16(wv);
        const float hf = __bfloat162float(h);
        __hip_bfloat16 l = __float2bfloat16(wv - hf);
        Afrags[fi]           = *(unsigned short*)&h;
        Afrags[NT * 512 + fi] = *(unsigned short*)&l;
    }
}

// ---------------- Kernel 2: Toeplitz MFMA conv, 64 outputs x 32 rows per wave ----------------
// Grid: (rows/32) x 16 blocks of 256 threads (4 waves). Block b: rt=b>>4, sg=b&15.
// Wave w: outputs [sg*256 + w*64, +64) for rows [rt*32, +32).
// Chunks c=0..19: t0 = n0-256+16c. Tile u in {0,1} uses chunks d+2u, d=0..17.
// 3 passes per (d,u): Ah*Bh + Ah*Bl + Al*Bh into fp32 acc.
__global__ void __launch_bounds__(256, 4)
frac_conv_mfma2(const float* __restrict__ x,
                const unsigned short* __restrict__ Afrags,
                float* __restrict__ out) {
    __shared__ __align__(16) unsigned short Asm[2 * NT * 512];  // 36 KB

    const int tid  = threadIdx.x;
    const int wave = tid >> 6;
    const int lane = tid & 63;
    const int l5   = lane >> 5;
    const int ln   = lane & 31;

    // stage A fragments into LDS: 36 KB = 9 x (256 threads x 16B), coalesced
    {
        const ushort8v* src = (const ushort8v*)Afrags;
        ushort8v* dst = (ushort8v*)Asm;
        #pragma unroll
        for (int i = 0; i < 9; ++i) dst[i * 256 + tid] = src[i * 256 + tid];
    }

    const int rt = blockIdx.x >> 4;
    const int sg = blockIdx.x & 15;
    const int n0 = sg * 256 + wave * 64;
    const int row = rt * 32 + ln;
    const float* __restrict__ xr = x + (size_t)row * TLEN + 8 * l5;
    float* __restrict__ orow = out + (size_t)row * TLEN;

    __syncthreads();

    bf16x8 Bh[NCH], Bl[NCH];

    auto LOADCVT = [&](int c) {
        const int t0 = n0 - 256 + 16 * c;
        if (t0 < 0) {
            const ushort8v z = {0, 0, 0, 0, 0, 0, 0, 0};
            Bh[c] = __builtin_bit_cast(bf16x8, z);
            Bl[c] = __builtin_bit_cast(bf16x8, z);
        } else {
            const float4 v0 = *(const float4*)(xr + t0);
            const float4 v1 = *(const float4*)(xr + t0 + 4);
            const float vf[8] = {v0.x, v0.y, v0.z, v0.w, v1.x, v1.y, v1.z, v1.w};
            ushort8v hb, lb;
            #pragma unroll
            for (int e = 0; e < 8; ++e) {
                const unsigned int u  = __float_as_uint(vf[e]);
                const unsigned int ht = u & 0xFFFF0000u;      // truncated hi (exact remainder)
                const float lf = vf[e] - __uint_as_float(ht);
                hb[e] = (unsigned short)(ht >> 16);
                lb[e] = (unsigned short)(__float_as_uint(lf) >> 16);
            }
            Bh[c] = __builtin_bit_cast(bf16x8, hb);
            Bl[c] = __builtin_bit_cast(bf16x8, lb);
        }
    };

    // prologue: first 4 chunks
    LOADCVT(0); LOADCVT(1); LOADCVT(2); LOADCVT(3);

    f32x16 acc0 = {0.f, 0.f, 0.f, 0.f, 0.f, 0.f, 0.f, 0.f,
                   0.f, 0.f, 0.f, 0.f, 0.f, 0.f, 0.f, 0.f};
    f32x16 acc1 = acc0;

    const ushort8v* Ah_lds = (const ushort8v*)Asm;
    const ushort8v* Al_lds = (const ushort8v*)(Asm + NT * 512);

    #pragma unroll
    for (int d = 0; d < NT; ++d) {
        if (d + 4 < NCH) LOADCVT(d + 4);   // rolling prefetch, 2-step lead
        const bf16x8 ah = __builtin_bit_cast(bf16x8, Ah_lds[d * 64 + lane]);
        const bf16x8 al = __builtin_bit_cast(bf16x8, Al_lds[d * 64 + lane]);
        acc0 = __builtin_amdgcn_mfma_f32_32x32x16_bf16(ah, Bh[d],     acc0, 0, 0, 0);
        acc1 = __builtin_amdgcn_mfma_f32_32x32x16_bf16(ah, Bh[d + 2], acc1, 0, 0, 0);
        acc0 = __builtin_amdgcn_mfma_f32_32x32x16_bf16(ah, Bl[d],     acc0, 0, 0, 0);
        acc1 = __builtin_amdgcn_mfma_f32_32x32x16_bf16(ah, Bl[d + 2], acc1, 0, 0, 0);
        acc0 = __builtin_amdgcn_mfma_f32_32x32x16_bf16(al, Bh[d],     acc0, 0, 0, 0);
        acc1 = __builtin_amdgcn_mfma_f32_32x32x16_bf16(al, Bh[d + 2], acc1, 0, 0, 0);
    }

    // D layout: col = lane&31 (row ln), m = (reg&3) + 8*(reg>>2) + 4*l5
    #pragma unroll
    for (int g = 0; g < 4; ++g) {
        *(float4*)(orow + n0 + 8 * g + 4 * l5) =
            make_float4(acc0[4 * g + 0], acc0[4 * g + 1], acc0[4 * g + 2], acc0[4 * g + 3]);
        *(float4*)(orow + n0 + 32 + 8 * g + 4 * l5) =
            make_float4(acc1[4 * g + 0], acc1[4 * g + 1], acc1[4 * g + 2], acc1[4 * g + 3]);
    }
}

// ---------------- Fallback path (proven round-1 fp32 kernels) ----------------
__global__ void gl_coeff_kernel(const float* __restrict__ loc,
                                const float* __restrict__ scale,
                                const float* __restrict__ eps,
                                float* __restrict__ w_out) {
    __shared__ float s[KTAPS];
    const int j = threadIdx.x;
    const float alpha = loc[0] + log1pf(expf(scale[0])) * eps[0];
    float f = (j == 0) ? 1.0f : (((float)j - 1.0f - alpha) / (float)j);
    s[j] = f;
    __syncthreads();
    #pragma unroll
    for (int st = 1; st < KTAPS; st <<= 1) {
        float v = s[j];
        float p = (j >= st) ? s[j - st] : 1.0f;
        __syncthreads();
        s[j] = v * p;
        __syncthreads();
    }
    w_out[j] = s[j];
}

__global__ void __launch_bounds__(256)
frac_conv_kernel(const float* __restrict__ x,
                 const float* __restrict__ w,
                 float* __restrict__ out) {
    __shared__ __align__(16) float xs[KTAPS + TLEN];
    __shared__ __align__(16) float wl[KTAPS];
    const int row = blockIdx.x;
    const int tid = threadIdx.x;
    const float* __restrict__ xr = x + (size_t)row * TLEN;
    float* __restrict__ orow = out + (size_t)row * TLEN;
    if (tid < 64) ((float4*)xs)[tid] = make_float4(0.f, 0.f, 0.f, 0.f);
    float4* xs4w = (float4*)(xs + KTAPS);
    const float4* xr4 = (const float4*)xr;
    #pragma unroll
    for (int k = 0; k < 4; ++k) xs4w[tid + k * 256] = xr4[tid + k * 256];
    if (tid < 64) ((float4*)wl)[tid] = ((const float4*)w)[tid];
    __syncthreads();
    const float4* __restrict__ xsv = (const float4*)xs;
    float4 acc[4]; float4 lo[4], hi[4]; int n0[4];
    #pragma unroll
    for (int g = 0; g < 4; ++g) {
        n0[g] = (tid << 2) + (g << 10);
        acc[g] = make_float4(0.f, 0.f, 0.f, 0.f);
        const int c = n0[g] >> 2;
        hi[g] = xsv[64 + c];
        lo[g] = xsv[63 + c];
    }
    #pragma unroll 4
    for (int j = 0; j < KTAPS - 4; j += 4) {
        const float4 w4 = *(const float4*)(wl + j);
        #pragma unroll
        for (int g = 0; g < 4; ++g) {
            acc[g].x += w4.x*hi[g].x + w4.y*lo[g].w + w4.z*lo[g].z + w4.w*lo[g].y;
            acc[g].y += w4.x*hi[g].y + w4.y*hi[g].x + w4.z*lo[g].w + w4.w*lo[g].z;
            acc[g].z += w4.x*hi[g].z + w4.y*hi[g].y + w4.z*hi[g].x + w4.w*lo[g].w;
            acc[g].w += w4.x*hi[g].w + w4.y*hi[g].z + w4.z*hi[g].y + w4.w*hi[g].x;
            hi[g] = lo[g];
            lo[g] = xsv[64 + ((n0[g] - j - 8) >> 2)];
        }
    }
    {
        const float4 w4 = *(const float4*)(wl + (KTAPS - 4));
        #pragma unroll
        for (int g = 0; g < 4; ++g) {
            acc[g].x += w4.x*hi[g].x + w4.y*lo[g].w + w4.z*lo[g].z + w4.w*lo[g].y;
            acc[g].y += w4.x*hi[g].y + w4.y*hi[g].x + w4.z*lo[g].w + w4.w*lo[g].z;
            acc[g].z += w4.x*hi[g].z + w4.y*hi[g].y + w4.z*hi[g].x + w4.w*lo[g].w;
            acc[g].w += w4.x*hi[g].w + w4.y*hi[g].z + w4.z*hi[g].y + w4.w*hi[g].x;
        }
    }
    #pragma unroll
    for (int g = 0; g < 4; ++g) *(float4*)(orow + n0[g]) = acc[g];
}

extern "C" void kernel_launch(void* const* d_in, const int* in_sizes, int n_in,
                              void* d_out, int out_size, void* d_ws, size_t ws_size,
                              hipStream_t stream) {
    const float* x     = (const float*)d_in[0];
    const float* loc   = (const float*)d_in[1];
    const float* scale = (const float*)d_in[2];
    const float* eps   = (const float*)d_in[3];
    float* out = (float*)d_out;
    const int rows = in_sizes[0] / TLEN;  // 2048

    const size_t neededA = 1024 + (size_t)2 * NT * 512 * 2;  // 37888 B
    if (ws_size >= neededA && (rows % 32) == 0) {
        unsigned short* A = (unsigned short*)((char*)d_ws + 1024);
        gl_coeff_frag_kernel<<<1, 256, 0, stream>>>(loc, scale, eps, A);
        frac_conv_mfma2<<<(rows / 32) * 16, 256, 0, stream>>>(x, A, out);
    } else {
        float* w = (float*)d_ws;
        gl_coeff_kernel<<<1, 256, 0, stream>>>(loc, scale, eps, w);
        frac_conv_kernel<<<rows, 256, 0, stream>>>(x, w, out);
    }
}

// Round 5
// 30.999 us; speedup vs baseline: 3.4428x; 1.2870x over previous
//
#include <hip/hip_runtime.h>
#include <hip/hip_bf16.h>
#include <hip/hip_fp16.h>

#define TLEN 4096
#define KTAPS 256
#define NT 18     // Toeplitz A tiles (K window = 288 = 18*16)
#define WCH 32    // B window chunks per block (512 floats)

typedef __attribute__((ext_vector_type(8))) unsigned short ushort8v;
typedef __attribute__((ext_vector_type(8))) _Float16 f16x8;
typedef __attribute__((ext_vector_type(16))) float f32x16;

// ---------------- Kernel 1: GL coeffs -> fp16 Toeplitz A-fragments ----------------
// A-tile d: W_d[m][k] = w[256 - 16d + m - k], m in [0,32), k in [0,16), 0 outside.
// mfma_f32_32x32x16_f16 A layout: lane l holds row m=l&31, k = 8*(l>>5)+e.
// Afrags[d*512 + lane*8 + e], fp16 bits. Grid = 36 blocks; every block redoes the
// cheap scan, block b writes slice [b*256, b*256+256).
__global__ void gl_coeff_frag_f16(const float* __restrict__ loc,
                                  const float* __restrict__ scale,
                                  const float* __restrict__ eps,
                                  unsigned short* __restrict__ Afrags) {
    __shared__ float s[KTAPS];
    const int j = threadIdx.x;
    const float alpha = loc[0] + log1pf(expf(scale[0])) * eps[0];
    float f = (j == 0) ? 1.0f : (((float)j - 1.0f - alpha) / (float)j);
    s[j] = f;
    __syncthreads();
    #pragma unroll
    for (int st = 1; st < KTAPS; st <<= 1) {
        float v = s[j];
        float p = (j >= st) ? s[j - st] : 1.0f;
        __syncthreads();
        s[j] = v * p;
        __syncthreads();
    }
    const int fi = blockIdx.x * 256 + j;      // < 18*512 = 9216
    const int tile = fi >> 9;
    const int lane = (fi >> 3) & 63;
    const int e    = fi & 7;
    const int m    = lane & 31;
    const int k    = 8 * (lane >> 5) + e;
    const int idx  = 256 - 16 * tile + m - k;
    const float wv = (idx >= 0 && idx < KTAPS) ? s[idx] : 0.0f;
    const _Float16 h = (_Float16)wv;          // round-to-nearest
    Afrags[fi] = __builtin_bit_cast(unsigned short, h);
}

// ---------------- Kernel 2: LDS-staged Toeplitz MFMA conv (fp16 single-pass) -------
// Grid: (rows/32) x 16 blocks of 256 threads (4 waves). Block: rt=b>>4, sg=b&15,
// covers rows [rt*32,+32) x outputs [sg*256,+256); window t in [sg*256-256, +512).
// Stage: coalesced fp32 loads -> cvt_pkrtz fp16 -> ds_write into fragment layout.
// Compute: wave w does outputs [n0,+64), local chunks lcb=w*4 .. lcb+19, 2 MFMAs/step.
__global__ void __launch_bounds__(256, 3)
frac_conv_mfma3(const float* __restrict__ x,
                const unsigned short* __restrict__ Afrags,
                float* __restrict__ out) {
    __shared__ __align__(16) unsigned short Asm[NT * 512];        // 18 KB
    __shared__ __align__(16) unsigned short Bf[WCH * 64 * 8];     // 32 KB

    const int tid  = threadIdx.x;
    const int wave = tid >> 6;
    const int lane = tid & 63;
    const int l5   = lane >> 5;
    const int ln   = lane & 31;
    const int rt   = blockIdx.x >> 4;
    const int sg   = blockIdx.x & 15;
    const int bn0  = sg * 256;

    // ---- stage A fragments: 9216 ushorts = 1152 x 16B, coalesced ----
    {
        const ushort8v* src = (const ushort8v*)Afrags;
        ushort8v* dst = (ushort8v*)Asm;
        #pragma unroll
        for (int i = 0; i < 4; ++i) dst[i * 256 + tid] = src[i * 256 + tid];
        if (tid < 128) dst[1024 + tid] = src[1024 + tid];
    }

    // ---- stage B window: 32 rows x 512 floats, coalesced reads, frag-layout writes ----
    {
        const int r  = tid >> 3;          // row 0..31
        const int cg = tid & 7;           // 8 threads/row -> 128B contiguous segments
        const float* __restrict__ xrow = x + (size_t)(rt * 32 + r) * TLEN;
        uint2* Bf2 = (uint2*)Bf;          // 8B units
        #pragma unroll
        for (int jj = 0; jj < 16; ++jj) {
            const int w0 = cg * 4 + jj * 32;      // float offset in window [0,512)
            const int tg = bn0 - 256 + w0;        // global t of first elem
            unsigned int p0 = 0, p1 = 0;
            if (tg >= 0) {
                const float4 v = *(const float4*)(xrow + tg);
                const auto a = __builtin_amdgcn_cvt_pkrtz(v.x, v.y);
                const auto b = __builtin_amdgcn_cvt_pkrtz(v.z, v.w);
                p0 = __builtin_bit_cast(unsigned int, a);
                p1 = __builtin_bit_cast(unsigned int, b);
            }
            // fragment position: chunk c, lane = r + 32*(k-half), elems e0..e0+3
            const int c  = w0 >> 4;
            const int h8 = (w0 >> 3) & 1;
            const int e0 = w0 & 7;                // 0 or 4
            const int uoff = (c * 64 + r + 32 * h8) * 8 + e0;  // ushort offset, 8B-aligned
            Bf2[uoff >> 2] = make_uint2(p0, p1);
        }
    }
    __syncthreads();

    // ---- compute: 18 steps, rolling LDS reads (all-constant indices after unroll) ----
    const int n0  = bn0 + wave * 64;
    const int lcb = wave * 4;
    const f16x8* Av = (const f16x8*)Asm;
    const f16x8* Bv = (const f16x8*)Bf;

    f16x8 Afr[NT];
    f16x8 Bfr[NT + 2];
    Bfr[0] = Bv[(lcb + 0) * 64 + lane];
    Bfr[1] = Bv[(lcb + 1) * 64 + lane];
    Bfr[2] = Bv[(lcb + 2) * 64 + lane];
    Bfr[3] = Bv[(lcb + 3) * 64 + lane];
    Afr[0] = Av[0 * 64 + lane];
    Afr[1] = Av[1 * 64 + lane];

    f32x16 acc0 = {0.f, 0.f, 0.f, 0.f, 0.f, 0.f, 0.f, 0.f,
                   0.f, 0.f, 0.f, 0.f, 0.f, 0.f, 0.f, 0.f};
    f32x16 acc1 = acc0;

    #pragma unroll
    for (int d = 0; d < NT; ++d) {
        if (d + 4 < NT + 2) Bfr[d + 4] = Bv[(lcb + d + 4) * 64 + lane];
        if (d + 2 < NT)     Afr[d + 2] = Av[(d + 2) * 64 + lane];
        acc0 = __builtin_amdgcn_mfma_f32_32x32x16_f16(Afr[d], Bfr[d],     acc0, 0, 0, 0);
        acc1 = __builtin_amdgcn_mfma_f32_32x32x16_f16(Afr[d], Bfr[d + 2], acc1, 0, 0, 0);
    }

    // D layout: col = lane&31 (row ln), m = (reg&3) + 8*(reg>>2) + 4*l5
    float* __restrict__ orow = out + (size_t)(rt * 32 + ln) * TLEN;
    #pragma unroll
    for (int g = 0; g < 4; ++g) {
        *(float4*)(orow + n0 + 8 * g + 4 * l5) =
            make_float4(acc0[4 * g + 0], acc0[4 * g + 1], acc0[4 * g + 2], acc0[4 * g + 3]);
        *(float4*)(orow + n0 + 32 + 8 * g + 4 * l5) =
            make_float4(acc1[4 * g + 0], acc1[4 * g + 1], acc1[4 * g + 2], acc1[4 * g + 3]);
    }
}

// ---------------- Fallback path (proven round-1 fp32 kernels) ----------------
__global__ void gl_coeff_kernel(const float* __restrict__ loc,
                                const float* __restrict__ scale,
                                const float* __restrict__ eps,
                                float* __restrict__ w_out) {
    __shared__ float s[KTAPS];
    const int j = threadIdx.x;
    const float alpha = loc[0] + log1pf(expf(scale[0])) * eps[0];
    float f = (j == 0) ? 1.0f : (((float)j - 1.0f - alpha) / (float)j);
    s[j] = f;
    __syncthreads();
    #pragma unroll
    for (int st = 1; st < KTAPS; st <<= 1) {
        float v = s[j];
        float p = (j >= st) ? s[j - st] : 1.0f;
        __syncthreads();
        s[j] = v * p;
        __syncthreads();
    }
    w_out[j] = s[j];
}

__global__ void __launch_bounds__(256)
frac_conv_kernel(const float* __restrict__ x,
                 const float* __restrict__ w,
                 float* __restrict__ out) {
    __shared__ __align__(16) float xs[KTAPS + TLEN];
    __shared__ __align__(16) float wl[KTAPS];
    const int row = blockIdx.x;
    const int tid = threadIdx.x;
    const float* __restrict__ xr = x + (size_t)row * TLEN;
    float* __restrict__ orow = out + (size_t)row * TLEN;
    if (tid < 64) ((float4*)xs)[tid] = make_float4(0.f, 0.f, 0.f, 0.f);
    float4* xs4w = (float4*)(xs + KTAPS);
    const float4* xr4 = (const float4*)xr;
    #pragma unroll
    for (int k = 0; k < 4; ++k) xs4w[tid + k * 256] = xr4[tid + k * 256];
    if (tid < 64) ((float4*)wl)[tid] = ((const float4*)w)[tid];
    __syncthreads();
    const float4* __restrict__ xsv = (const float4*)xs;
    float4 acc[4]; float4 lo[4], hi[4]; int n0[4];
    #pragma unroll
    for (int g = 0; g < 4; ++g) {
        n0[g] = (tid << 2) + (g << 10);
        acc[g] = make_float4(0.f, 0.f, 0.f, 0.f);
        const int c = n0[g] >> 2;
        hi[g] = xsv[64 + c];
        lo[g] = xsv[63 + c];
    }
    #pragma unroll 4
    for (int j = 0; j < KTAPS - 4; j += 4) {
        const float4 w4 = *(const float4*)(wl + j);
        #pragma unroll
        for (int g = 0; g < 4; ++g) {
            acc[g].x += w4.x*hi[g].x + w4.y*lo[g].w + w4.z*lo[g].z + w4.w*lo[g].y;
            acc[g].y += w4.x*hi[g].y + w4.y*hi[g].x + w4.z*lo[g].w + w4.w*lo[g].z;
            acc[g].z += w4.x*hi[g].z + w4.y*hi[g].y + w4.z*hi[g].x + w4.w*lo[g].w;
            acc[g].w += w4.x*hi[g].w + w4.y*hi[g].z + w4.z*hi[g].y + w4.w*hi[g].x;
            hi[g] = lo[g];
            lo[g] = xsv[64 + ((n0[g] - j - 8) >> 2)];
        }
    }
    {
        const float4 w4 = *(const float4*)(wl + (KTAPS - 4));
        #pragma unroll
        for (int g = 0; g < 4; ++g) {
            acc[g].x += w4.x*hi[g].x + w4.y*lo[g].w + w4.z*lo[g].z + w4.w*lo[g].y;
            acc[g].y += w4.x*hi[g].y + w4.y*hi[g].x + w4.z*lo[g].w + w4.w*lo[g].z;
            acc[g].z += w4.x*hi[g].z + w4.y*hi[g].y + w4.z*hi[g].x + w4.w*lo[g].w;
            acc[g].w += w4.x*hi[g].w + w4.y*hi[g].z + w4.z*hi[g].y + w4.w*hi[g].x;
        }
    }
    #pragma unroll
    for (int g = 0; g < 4; ++g) *(float4*)(orow + n0[g]) = acc[g];
}

extern "C" void kernel_launch(void* const* d_in, const int* in_sizes, int n_in,
                              void* d_out, int out_size, void* d_ws, size_t ws_size,
                              hipStream_t stream) {
    const float* x     = (const float*)d_in[0];
    const float* loc   = (const float*)d_in[1];
    const float* scale = (const float*)d_in[2];
    const float* eps   = (const float*)d_in[3];
    float* out = (float*)d_out;
    const int rows = in_sizes[0] / TLEN;  // 2048

    const size_t neededA = 1024 + (size_t)NT * 512 * 2;  // 19456 B
    if (ws_size >= neededA && (rows % 32) == 0) {
        unsigned short* A = (unsigned short*)((char*)d_ws + 1024);
        gl_coeff_frag_f16<<<NT * 2, 256, 0, stream>>>(loc, scale, eps, A);
        frac_conv_mfma3<<<(rows / 32) * 16, 256, 0, stream>>>(x, A, out);
    } else {
        float* w = (float*)d_ws;
        gl_coeff_kernel<<<1, 256, 0, stream>>>(loc, scale, eps, w);
        frac_conv_kernel<<<rows, 256, 0, stream>>>(x, w, out);
    }
}

// Round 6
// 18.813 us; speedup vs baseline: 5.6728x; 1.6477x over previous
//
#include <hip/hip_runtime.h>
#include <hip/hip_bf16.h>
#include <hip/hip_fp16.h>

#define TLEN 4096
#define KTAPS 256
#define NT 18     // Toeplitz A tiles (K window = 288 = 18*16)
#define WCH 32    // B window chunks per block (512 floats)

typedef __attribute__((ext_vector_type(8))) unsigned short ushort8v;
typedef __attribute__((ext_vector_type(8))) _Float16 f16x8;
typedef __attribute__((ext_vector_type(4))) unsigned int uint4v;
typedef __attribute__((ext_vector_type(16))) float f32x16;

// ---------------- Fused kernel: scan + tap table + LDS-staged Toeplitz MFMA -------
// Grid: (rows/32) x 16 blocks of 256 threads (4 waves). Block covers rows
// [rt*32,+32) x outputs [sg*256,+256); window t in [sg*256-256, sg*256+256).
// Phases: (1) burst-issue 16 float4 B loads  (2) GL cumprod scan in LDS
// (3) build reversed packed fp16 tap table wrevp  (4) convert B -> fp16 frags in LDS
// (5) 18-step MFMA loop, A-fragments read on-the-fly from wrevp.
__global__ void __launch_bounds__(256, 4)
frac_conv_fused(const float* __restrict__ x,
                const float* __restrict__ loc,
                const float* __restrict__ scale,
                const float* __restrict__ eps,
                float* __restrict__ out) {
    __shared__ float s[KTAPS];                               // 1 KB
    __shared__ unsigned int wrevp[320];                      // 1.25 KB
    __shared__ __align__(16) unsigned short Bf[WCH * 64 * 8]; // 32 KB

    const int tid  = threadIdx.x;
    const int wave = tid >> 6;
    const int lane = tid & 63;
    const int l5   = lane >> 5;
    const int ln   = lane & 31;

    // XCD-aware swizzle: keep the 16 sg-blocks of one row-tile on one XCD's L2.
    int rt, sg;
    if ((gridDim.x & 127) == 0) {              // nrt % 8 == 0 -> bijective swizzle
        const int nrt  = gridDim.x >> 4;
        const int xcd  = blockIdx.x & 7;
        const int slot = blockIdx.x >> 3;
        rt = xcd * (nrt >> 3) + (slot >> 4);
        sg = slot & 15;
    } else {
        rt = blockIdx.x >> 4;
        sg = blockIdx.x & 15;
    }
    const int bn0 = sg * 256;

    // ---- phase 1: burst-issue B window loads (32 rows x 512 floats, coalesced) ----
    const int r  = tid >> 3;          // row 0..31
    const int cg = tid & 7;           // 8 threads/row, 128B contiguous segments
    const float* __restrict__ xrow = x + (size_t)(rt * 32 + r) * TLEN;
    float4 v[16];
    #pragma unroll
    for (int jj = 0; jj < 16; ++jj) {
        const int w0 = cg * 4 + jj * 32;          // float offset in window [0,512)
        const int tg = bn0 - 256 + w0;            // global t of first elem
        v[jj] = (tg >= 0) ? *(const float4*)(xrow + tg) : make_float4(0.f, 0.f, 0.f, 0.f);
    }

    // ---- phase 2: GL coefficient cumprod scan (fp32, LDS) ----
    const float alpha = loc[0] + log1pf(expf(scale[0])) * eps[0];
    {
        const float f = (tid == 0) ? 1.0f : (((float)tid - 1.0f - alpha) / (float)tid);
        s[tid] = f;
        __syncthreads();
        #pragma unroll
        for (int st = 1; st < KTAPS; st <<= 1) {
            const float vv = s[tid];
            const float p  = (tid >= st) ? s[tid - st] : 1.0f;
            __syncthreads();
            s[tid] = vv * p;
            __syncthreads();
        }
    }

    // ---- phase 3: reversed packed fp16 tap table ----
    // wrev[j] = w[287-j] for 32<=j<=287, else 0;  wrevp[j] = pack(wrev[j], wrev[j+1])
    {
        const int j = tid;                         // 0..255
        const float a = (j >= 32) ? s[287 - j] : 0.0f;
        const float b = (j >= 31 && j <= 286) ? s[286 - j] : 0.0f;
        wrevp[j] = __builtin_bit_cast(unsigned int, __builtin_amdgcn_cvt_pkrtz(a, b));
        if (tid < 64) {
            const int j2 = 256 + tid;              // 256..319
            const float a2 = (j2 <= 287) ? s[287 - j2] : 0.0f;
            const float b2 = (j2 <= 286) ? s[286 - j2] : 0.0f;
            wrevp[j2] = __builtin_bit_cast(unsigned int, __builtin_amdgcn_cvt_pkrtz(a2, b2));
        }
    }

    // ---- phase 4: convert B to fp16 fragments in LDS ----
    {
        uint2* Bf2 = (uint2*)Bf;
        #pragma unroll
        for (int jj = 0; jj < 16; ++jj) {
            const int w0 = cg * 4 + jj * 32;
            const auto a = __builtin_amdgcn_cvt_pkrtz(v[jj].x, v[jj].y);
            const auto b = __builtin_amdgcn_cvt_pkrtz(v[jj].z, v[jj].w);
            const int c  = w0 >> 4;                // chunk
            const int h8 = (w0 >> 3) & 1;          // k-half
            const int e0 = w0 & 7;                 // 0 or 4
            const int uoff = (c * 64 + r + 32 * h8) * 8 + e0;  // ushort offset
            Bf2[uoff >> 2] = make_uint2(__builtin_bit_cast(unsigned int, a),
                                        __builtin_bit_cast(unsigned int, b));
        }
    }
    __syncthreads();

    // ---- phase 5: MFMA loop; A-fragments on the fly from wrevp ----
    const int n0  = bn0 + wave * 64;
    const int lcb = wave * 4;
    const f16x8* Bv = (const f16x8*)Bf;
    const int o0 = 31 - ln + 8 * l5;   // tap-table base for this lane

    auto LOADA = [&](int d) -> f16x8 {
        const int o = o0 + 16 * d;
        uint4v u;
        u[0] = wrevp[o];
        u[1] = wrevp[o + 2];
        u[2] = wrevp[o + 4];
        u[3] = wrevp[o + 6];
        return __builtin_bit_cast(f16x8, u);
    };

    f16x8 Afr[NT];
    f16x8 Bfr[NT + 2];
    Bfr[0] = Bv[(lcb + 0) * 64 + lane];
    Bfr[1] = Bv[(lcb + 1) * 64 + lane];
    Bfr[2] = Bv[(lcb + 2) * 64 + lane];
    Bfr[3] = Bv[(lcb + 3) * 64 + lane];
    Afr[0] = LOADA(0);
    Afr[1] = LOADA(1);

    f32x16 acc0 = {0.f, 0.f, 0.f, 0.f, 0.f, 0.f, 0.f, 0.f,
                   0.f, 0.f, 0.f, 0.f, 0.f, 0.f, 0.f, 0.f};
    f32x16 acc1 = acc0;

    #pragma unroll
    for (int d = 0; d < NT; ++d) {
        if (d + 4 < NT + 2) Bfr[d + 4] = Bv[(lcb + d + 4) * 64 + lane];
        if (d + 2 < NT)     Afr[d + 2] = LOADA(d + 2);
        acc0 = __builtin_amdgcn_mfma_f32_32x32x16_f16(Afr[d], Bfr[d],     acc0, 0, 0, 0);
        acc1 = __builtin_amdgcn_mfma_f32_32x32x16_f16(Afr[d], Bfr[d + 2], acc1, 0, 0, 0);
    }

    // D layout: col = lane&31 (row ln), m = (reg&3) + 8*(reg>>2) + 4*l5
    float* __restrict__ orow = out + (size_t)(rt * 32 + ln) * TLEN;
    #pragma unroll
    for (int g = 0; g < 4; ++g) {
        *(float4*)(orow + n0 + 8 * g + 4 * l5) =
            make_float4(acc0[4 * g + 0], acc0[4 * g + 1], acc0[4 * g + 2], acc0[4 * g + 3]);
        *(float4*)(orow + n0 + 32 + 8 * g + 4 * l5) =
            make_float4(acc1[4 * g + 0], acc1[4 * g + 1], acc1[4 * g + 2], acc1[4 * g + 3]);
    }
}

// ---------------- Fallback path (proven round-1 fp32 kernels) ----------------
__global__ void gl_coeff_kernel(const float* __restrict__ loc,
                                const float* __restrict__ scale,
                                const float* __restrict__ eps,
                                float* __restrict__ w_out) {
    __shared__ float s[KTAPS];
    const int j = threadIdx.x;
    const float alpha = loc[0] + log1pf(expf(scale[0])) * eps[0];
    float f = (j == 0) ? 1.0f : (((float)j - 1.0f - alpha) / (float)j);
    s[j] = f;
    __syncthreads();
    #pragma unroll
    for (int st = 1; st < KTAPS; st <<= 1) {
        float v = s[j];
        float p = (j >= st) ? s[j - st] : 1.0f;
        __syncthreads();
        s[j] = v * p;
        __syncthreads();
    }
    w_out[j] = s[j];
}

__global__ void __launch_bounds__(256)
frac_conv_kernel(const float* __restrict__ x,
                 const float* __restrict__ w,
                 float* __restrict__ out) {
    __shared__ __align__(16) float xs[KTAPS + TLEN];
    __shared__ __align__(16) float wl[KTAPS];
    const int row = blockIdx.x;
    const int tid = threadIdx.x;
    const float* __restrict__ xr = x + (size_t)row * TLEN;
    float* __restrict__ orow = out + (size_t)row * TLEN;
    if (tid < 64) ((float4*)xs)[tid] = make_float4(0.f, 0.f, 0.f, 0.f);
    float4* xs4w = (float4*)(xs + KTAPS);
    const float4* xr4 = (const float4*)xr;
    #pragma unroll
    for (int k = 0; k < 4; ++k) xs4w[tid + k * 256] = xr4[tid + k * 256];
    if (tid < 64) ((float4*)wl)[tid] = ((const float4*)w)[tid];
    __syncthreads();
    const float4* __restrict__ xsv = (const float4*)xs;
    float4 acc[4]; float4 lo[4], hi[4]; int n0[4];
    #pragma unroll
    for (int g = 0; g < 4; ++g) {
        n0[g] = (tid << 2) + (g << 10);
        acc[g] = make_float4(0.f, 0.f, 0.f, 0.f);
        const int c = n0[g] >> 2;
        hi[g] = xsv[64 + c];
        lo[g] = xsv[63 + c];
    }
    #pragma unroll 4
    for (int j = 0; j < KTAPS - 4; j += 4) {
        const float4 w4 = *(const float4*)(wl + j);
        #pragma unroll
        for (int g = 0; g < 4; ++g) {
            acc[g].x += w4.x*hi[g].x + w4.y*lo[g].w + w4.z*lo[g].z + w4.w*lo[g].y;
            acc[g].y += w4.x*hi[g].y + w4.y*hi[g].x + w4.z*lo[g].w + w4.w*lo[g].z;
            acc[g].z += w4.x*hi[g].z + w4.y*hi[g].y + w4.z*hi[g].x + w4.w*lo[g].w;
            acc[g].w += w4.x*hi[g].w + w4.y*hi[g].z + w4.z*hi[g].y + w4.w*hi[g].x;
            hi[g] = lo[g];
            lo[g] = xsv[64 + ((n0[g] - j - 8) >> 2)];
        }
    }
    {
        const float4 w4 = *(const float4*)(wl + (KTAPS - 4));
        #pragma unroll
        for (int g = 0; g < 4; ++g) {
            acc[g].x += w4.x*hi[g].x + w4.y*lo[g].w + w4.z*lo[g].z + w4.w*lo[g].y;
            acc[g].y += w4.x*hi[g].y + w4.y*hi[g].x + w4.z*lo[g].w + w4.w*lo[g].z;
            acc[g].z += w4.x*hi[g].z + w4.y*hi[g].y + w4.z*hi[g].x + w4.w*lo[g].w;
            acc[g].w += w4.x*hi[g].w + w4.y*hi[g].z + w4.z*hi[g].y + w4.w*hi[g].x;
        }
    }
    #pragma unroll
    for (int g = 0; g < 4; ++g) *(float4*)(orow + n0[g]) = acc[g];
}

extern "C" void kernel_launch(void* const* d_in, const int* in_sizes, int n_in,
                              void* d_out, int out_size, void* d_ws, size_t ws_size,
                              hipStream_t stream) {
    const float* x     = (const float*)d_in[0];
    const float* loc   = (const float*)d_in[1];
    const float* scale = (const float*)d_in[2];
    const float* eps   = (const float*)d_in[3];
    float* out = (float*)d_out;
    const int rows = in_sizes[0] / TLEN;  // 2048

    if ((rows % 32) == 0) {
        frac_conv_fused<<<(rows / 32) * 16, 256, 0, stream>>>(x, loc, scale, eps, out);
    } else {
        float* w = (float*)d_ws;
        gl_coeff_kernel<<<1, 256, 0, stream>>>(loc, scale, eps, w);
        frac_conv_kernel<<<rows, 256, 0, stream>>>(x, w, out);
    }
}